// Round 1
// baseline (4507.491 us; speedup 1.0000x reference)
//
#include <hip/hip_runtime.h>
#include <hip/hip_bf16.h>

#define BATCHN 128
#define SEQT   2048
#define FEAT   64
#define UNITS  64
#define NCOL   256   // 4*UNITS gate columns
#define OUTD   6

__device__ __forceinline__ float fast_exp2(float x) {
#if __has_builtin(__builtin_amdgcn_exp2f)
    return __builtin_amdgcn_exp2f(x);
#else
    return exp2f(x);
#endif
}
__device__ __forceinline__ float fast_rcp(float x) {
#if __has_builtin(__builtin_amdgcn_rcpf)
    return __builtin_amdgcn_rcpf(x);
#else
    return 1.0f / x;
#endif
}
__device__ __forceinline__ float sig_(float x) {
    // 1/(1+2^(-x*log2e))
    return fast_rcp(1.0f + fast_exp2(-1.4426950408889634f * x));
}
__device__ __forceinline__ float tanh_(float x) {
    float xc = fminf(fmaxf(x, -15.0f), 15.0f);   // avoid inf/inf
    float e  = fast_exp2(2.8853900817779268f * xc);  // 2^(2x*log2e) = e^(2x)
    return (e - 1.0f) * fast_rcp(e + 1.0f);
}

__global__ __launch_bounds__(256, 1)
void lstm3_persistent(const float* __restrict__ x,
                      const float* __restrict__ W0, const float* __restrict__ U0,
                      const float* __restrict__ b0,
                      const float* __restrict__ W1, const float* __restrict__ U1,
                      const float* __restrict__ b1,
                      const float* __restrict__ Wf, const float* __restrict__ bfv,
                      const float* __restrict__ Wo, const float* __restrict__ bov,
                      float* __restrict__ out)
{
    const int b    = blockIdx.x;     // batch row
    const int tid  = threadIdx.x;    // 0..255
    const int unit = tid >> 2;       // 0..63
    const int gate = tid & 3;        // 0..3 (i,f,g,o)
    const int col  = (gate << 6) + unit;  // column in z
    const int lane = tid & 63;
    const int qb   = lane & ~3;      // quad base lane in wave

    __shared__ float lx[2][FEAT];
    __shared__ float lh0[2][UNITS], lh1[2][UNITS], lh2[2][UNITS];
    __shared__ float lact[UNITS];

    // per-thread weight columns in registers (256 VGPRs)
    float w0[FEAT], u0[UNITS], w1r[UNITS], u1r[UNITS];
#pragma unroll
    for (int k = 0; k < 64; ++k) {
        w0[k]  = W0[k * NCOL + col];
        u0[k]  = U0[k * NCOL + col];
        w1r[k] = W1[k * NCOL + col];
        u1r[k] = U1[k * NCOL + col];
    }
    const float bias0 = b0[col];
    const float bias1 = b1[col];

    const size_t xbase = (size_t)b * SEQT * FEAT;
    if (tid < FEAT) {
        lh0[0][tid] = 0.f; lh0[1][tid] = 0.f;
        lh1[0][tid] = 0.f; lh1[1][tid] = 0.f;
        lh2[0][tid] = 0.f; lh2[1][tid] = 0.f;
        lx[0][tid]  = x[xbase + tid];            // x(0)
    }
    float xreg = 0.f;
    if (tid < FEAT) xreg = x[xbase + FEAT + tid]; // x(1)
    __syncthreads();

    float c0 = 0.f, c1 = 0.f, c2 = 0.f;

    for (int t = 0; t < SEQT; ++t) {
        const int p = t & 1;        // h(t) buffers / x(t) buffer
        const int q = p ^ 1;        // h(t-1) buffers / x(t+1) buffer

        // stage x(t+1) (loaded last step) into LDS; prefetch x(t+2) into reg
        if (tid < FEAT) {
            if (t + 1 < SEQT) lx[q][tid] = xreg;
            if (t + 2 < SEQT) xreg = x[xbase + (size_t)(t + 2) * FEAT + tid];
        }

        // ---------------- layer 0 : z = x(t)@W0 + h0(t-1)@U0 + b0 ----------
        {
            float a0 = 0.f, a1 = 0.f, a2 = 0.f, a3 = 0.f;
#pragma unroll
            for (int k = 0; k < 16; ++k) {
                a0 += lx[p][k]      * w0[k];
                a1 += lx[p][k + 16] * w0[k + 16];
                a2 += lx[p][k + 32] * w0[k + 32];
                a3 += lx[p][k + 48] * w0[k + 48];
            }
#pragma unroll
            for (int k = 0; k < 16; ++k) {
                a0 += lh0[q][k]      * u0[k];
                a1 += lh0[q][k + 16] * u0[k + 16];
                a2 += lh0[q][k + 32] * u0[k + 32];
                a3 += lh0[q][k + 48] * u0[k + 48];
            }
            float z  = ((a0 + a1) + (a2 + a3)) + bias0;
            float zi = __shfl(z, qb + 0, 64);
            float zf = __shfl(z, qb + 1, 64);
            float zg = __shfl(z, qb + 2, 64);
            float zo = __shfl(z, qb + 3, 64);
            c0 = sig_(zf) * c0 + sig_(zi) * tanh_(zg);
            float hn = sig_(zo) * tanh_(c0);
            if (gate == 0) lh0[p][unit] = hn;
        }
        __syncthreads();   // h0(t) ready

        // ---------------- layer 1 : z = h0(t)@W1 + h1(t-1)@U1 + b1 ---------
        {
            float a0 = 0.f, a1 = 0.f, a2 = 0.f, a3 = 0.f;
#pragma unroll
            for (int k = 0; k < 16; ++k) {
                a0 += lh0[p][k]      * w1r[k];
                a1 += lh0[p][k + 16] * w1r[k + 16];
                a2 += lh0[p][k + 32] * w1r[k + 32];
                a3 += lh0[p][k + 48] * w1r[k + 48];
            }
#pragma unroll
            for (int k = 0; k < 16; ++k) {
                a0 += lh1[q][k]      * u1r[k];
                a1 += lh1[q][k + 16] * u1r[k + 16];
                a2 += lh1[q][k + 32] * u1r[k + 32];
                a3 += lh1[q][k + 48] * u1r[k + 48];
            }
            float z  = ((a0 + a1) + (a2 + a3)) + bias1;
            float zi = __shfl(z, qb + 0, 64);
            float zf = __shfl(z, qb + 1, 64);
            float zg = __shfl(z, qb + 2, 64);
            float zo = __shfl(z, qb + 3, 64);
            c1 = sig_(zf) * c1 + sig_(zi) * tanh_(zg);
            float hn = sig_(zo) * tanh_(c1);
            if (gate == 0) lh1[p][unit] = hn;
        }
        __syncthreads();   // h1(t) ready

        // ---------------- layer 2 : z = h1(t)@W1 + h2(t-1)@U1 + b1 ---------
        {
            float a0 = 0.f, a1 = 0.f, a2 = 0.f, a3 = 0.f;
#pragma unroll
            for (int k = 0; k < 16; ++k) {
                a0 += lh1[p][k]      * w1r[k];
                a1 += lh1[p][k + 16] * w1r[k + 16];
                a2 += lh1[p][k + 32] * w1r[k + 32];
                a3 += lh1[p][k + 48] * w1r[k + 48];
            }
#pragma unroll
            for (int k = 0; k < 16; ++k) {
                a0 += lh2[q][k]      * u1r[k];
                a1 += lh2[q][k + 16] * u1r[k + 16];
                a2 += lh2[q][k + 32] * u1r[k + 32];
                a3 += lh2[q][k + 48] * u1r[k + 48];
            }
            float z  = ((a0 + a1) + (a2 + a3)) + bias1;
            float zi = __shfl(z, qb + 0, 64);
            float zf = __shfl(z, qb + 1, 64);
            float zg = __shfl(z, qb + 2, 64);
            float zo = __shfl(z, qb + 3, 64);
            c2 = sig_(zf) * c2 + sig_(zi) * tanh_(zg);
            float hn = sig_(zo) * tanh_(c2);
            if (gate == 0) lh2[p][unit] = hn;
        }
        __syncthreads();   // h2(t) ready, end of step
    }

    // ---------------- dense head on final h2 (in lh2[(SEQT-1)&1]) ----------
    const float* h2f = lh2[(SEQT - 1) & 1];
    if (tid < UNITS) {
        float acc = bfv[tid];
#pragma unroll
        for (int k = 0; k < UNITS; ++k) acc += h2f[k] * Wf[k * 64 + tid];
        lact[tid] = fmaxf(acc, 0.f);
    }
    __syncthreads();
    if (tid < OUTD) {
        float acc = bov[tid];
#pragma unroll
        for (int k = 0; k < UNITS; ++k) acc += lact[k] * Wo[k * OUTD + tid];
        out[b * OUTD + tid] = acc;
    }
}

extern "C" void kernel_launch(void* const* d_in, const int* in_sizes, int n_in,
                              void* d_out, int out_size, void* d_ws, size_t ws_size,
                              hipStream_t stream) {
    const float* x   = (const float*)d_in[0];
    const float* W0  = (const float*)d_in[1];
    const float* U0  = (const float*)d_in[2];
    const float* b0  = (const float*)d_in[3];
    const float* W1  = (const float*)d_in[4];
    const float* U1  = (const float*)d_in[5];
    const float* b1  = (const float*)d_in[6];
    const float* Wf  = (const float*)d_in[7];
    const float* bfv = (const float*)d_in[8];
    const float* Wo  = (const float*)d_in[9];
    const float* bov = (const float*)d_in[10];
    float* out = (float*)d_out;

    lstm3_persistent<<<BATCHN, 256, 0, stream>>>(x, W0, U0, b0, W1, U1, b1,
                                                 Wf, bfv, Wo, bov, out);
}

// Round 2
// 3057.242 us; speedup vs baseline: 1.4744x; 1.4744x over previous
//
#include <hip/hip_runtime.h>

#define BATCHN 128
#define SEQT   2048
#define FEAT   64
#define UNITS  64
#define NCOL   256   // 4*UNITS gate columns
#define OUTD   6

__device__ __forceinline__ float fast_exp2(float x) {
#if __has_builtin(__builtin_amdgcn_exp2f)
    return __builtin_amdgcn_exp2f(x);
#else
    return exp2f(x);
#endif
}
__device__ __forceinline__ float fast_rcp(float x) {
#if __has_builtin(__builtin_amdgcn_rcpf)
    return __builtin_amdgcn_rcpf(x);
#else
    return 1.0f / x;
#endif
}
__device__ __forceinline__ float sig_(float x) {
    return fast_rcp(1.0f + fast_exp2(-1.4426950408889634f * x));
}
__device__ __forceinline__ float tanh_(float x) {
    float xc = fminf(fmaxf(x, -15.0f), 15.0f);
    float e  = fast_exp2(2.8853900817779268f * xc);  // e^(2x)
    return (e - 1.0f) * fast_rcp(e + 1.0f);
}

// DPP cross-lane move (VALU pipe, no LDS traffic)
template<int CTRL>
__device__ __forceinline__ float dppf(float v) {
    return __builtin_bit_cast(float, __builtin_amdgcn_update_dpp(
        0, __builtin_bit_cast(int, v), CTRL, 0xF, 0xF, true));
}
// full reduce across 8-lane k-split group (lanes differ in bits [2:0])
__device__ __forceinline__ float red8(float v) {
    v += dppf<0xB1>(v);    // quad_perm [1,0,3,2]  : xor 1
    v += dppf<0x4E>(v);    // quad_perm [2,3,0,1]  : xor 2
    v += dppf<0x141>(v);   // row_half_mirror (l^7): xor 4 after the above
    return v;
}

// one LSTM cell update for this thread's unit; ia/ib = input-vec k-chunk,
// ja/jb = recurrent h k-chunk; WA/WB = per-gate weight chunks.
__device__ __forceinline__ float cell_(const float (&WA)[4][8], const float (&WB)[4][8],
                                       const float (&bias)[4],
                                       float4 ia, float4 ib, float4 ja, float4 jb,
                                       float& c)
{
    float z[4];
#pragma unroll
    for (int g = 0; g < 4; ++g) {
        float a = 0.f, h = 0.f;
        a = fmaf(ia.x, WA[g][0], a); a = fmaf(ia.y, WA[g][1], a);
        a = fmaf(ia.z, WA[g][2], a); a = fmaf(ia.w, WA[g][3], a);
        a = fmaf(ib.x, WA[g][4], a); a = fmaf(ib.y, WA[g][5], a);
        a = fmaf(ib.z, WA[g][6], a); a = fmaf(ib.w, WA[g][7], a);
        h = fmaf(ja.x, WB[g][0], h); h = fmaf(ja.y, WB[g][1], h);
        h = fmaf(ja.z, WB[g][2], h); h = fmaf(ja.w, WB[g][3], h);
        h = fmaf(jb.x, WB[g][4], h); h = fmaf(jb.y, WB[g][5], h);
        h = fmaf(jb.z, WB[g][6], h); h = fmaf(jb.w, WB[g][7], h);
        z[g] = red8(a + h) + bias[g];
    }
    float ig = sig_(z[0]), fg = sig_(z[1]), gg = tanh_(z[2]), og = sig_(z[3]);
    c = fg * c + ig * gg;
    return og * tanh_(c);
}

__global__ __launch_bounds__(512, 2)
void lstm3_ksplit(const float* __restrict__ x,
                  const float* __restrict__ W0, const float* __restrict__ U0,
                  const float* __restrict__ b0,
                  const float* __restrict__ W1, const float* __restrict__ U1,
                  const float* __restrict__ b1,
                  const float* __restrict__ Wf, const float* __restrict__ bfv,
                  const float* __restrict__ Wo, const float* __restrict__ bov,
                  float* __restrict__ out)
{
    const int b   = blockIdx.x;
    const int tid = threadIdx.x;   // 0..511
    const int u   = tid >> 3;      // unit 0..63  (8 consecutive lanes per unit)
    const int q   = tid & 7;       // k-split 0..7

    __shared__ __align__(16) float lh0[2][UNITS];
    __shared__ __align__(16) float lh1[2][UNITS];
    __shared__ __align__(16) float lh2[2][UNITS];
    __shared__ float lact[UNITS];

    // per-thread weights: 4 gate cols of unit u, k-chunk [8q, 8q+8)  => 128 VGPRs
    float w0r[4][8], u0r[4][8], w1r[4][8], u1r[4][8];
    float bias0[4], bias1[4];
#pragma unroll
    for (int g = 0; g < 4; ++g) {
        const int col = (g << 6) + u;
#pragma unroll
        for (int k = 0; k < 8; ++k) {
            const int row = q * 8 + k;
            w0r[g][k] = W0[row * NCOL + col];
            u0r[g][k] = U0[row * NCOL + col];
            w1r[g][k] = W1[row * NCOL + col];
            u1r[g][k] = U1[row * NCOL + col];
        }
        bias0[g] = b0[col];
        bias1[g] = b1[col];
    }

    if (tid < UNITS) {
        lh0[0][tid] = 0.f; lh0[1][tid] = 0.f;
        lh1[0][tid] = 0.f; lh1[1][tid] = 0.f;
        lh2[0][tid] = 0.f; lh2[1][tid] = 0.f;
    }
    __syncthreads();

    const float* xrow = x + (size_t)b * SEQT * FEAT + q * 8;
    float4 xa = *(const float4*)(xrow);
    float4 xb = *(const float4*)(xrow + 4);

    float c0 = 0.f, c1 = 0.f, c2 = 0.f;

    for (int t = 0; t < SEQT; ++t) {
        const int p = t & 1, pr = p ^ 1;

        // ---- layer 0: x(t)@W0 + h0(t-1)@U0 ----
        float4 ha = *(const float4*)&lh0[pr][q * 8];
        float4 hb = *(const float4*)&lh0[pr][q * 8 + 4];
        float h0n = cell_(w0r, u0r, bias0, xa, xb, ha, hb, c0);
        if (q == 0) lh0[p][u] = h0n;

        // prefetch x(t+1) (global, L1-resident; hides under 2 layers of compute)
        float4 nxa = xa, nxb = xb;
        if (t + 1 < SEQT) {
            nxa = *(const float4*)(xrow + (size_t)(t + 1) * FEAT);
            nxb = *(const float4*)(xrow + (size_t)(t + 1) * FEAT + 4);
        }
        __syncthreads();

        // ---- layer 1: h0(t)@W1 + h1(t-1)@U1 ----
        float4 ia = *(const float4*)&lh0[p][q * 8];
        float4 ib = *(const float4*)&lh0[p][q * 8 + 4];
        float4 ja = *(const float4*)&lh1[pr][q * 8];
        float4 jb = *(const float4*)&lh1[pr][q * 8 + 4];
        float h1n = cell_(w1r, u1r, bias1, ia, ib, ja, jb, c1);
        if (q == 0) lh1[p][u] = h1n;
        __syncthreads();

        // ---- layer 2: h1(t)@W1 + h2(t-1)@U1 ----
        float4 ka = *(const float4*)&lh1[p][q * 8];
        float4 kb = *(const float4*)&lh1[p][q * 8 + 4];
        float4 ma = *(const float4*)&lh2[pr][q * 8];
        float4 mb = *(const float4*)&lh2[pr][q * 8 + 4];
        float h2n = cell_(w1r, u1r, bias1, ka, kb, ma, mb, c2);
        if (q == 0) lh2[p][u] = h2n;
        __syncthreads();

        xa = nxa; xb = nxb;
    }

    // ---- dense head on final h2 (in lh2[(SEQT-1)&1]) ----
    const float* h2f = lh2[(SEQT - 1) & 1];
    if (tid < UNITS) {
        float acc = bfv[tid];
#pragma unroll
        for (int k = 0; k < UNITS; ++k) acc += h2f[k] * Wf[k * 64 + tid];
        lact[tid] = fmaxf(acc, 0.f);
    }
    __syncthreads();
    if (tid < OUTD) {
        float acc = bov[tid];
#pragma unroll
        for (int k = 0; k < UNITS; ++k) acc += lact[k] * Wo[k * OUTD + tid];
        out[b * OUTD + tid] = acc;
    }
}

extern "C" void kernel_launch(void* const* d_in, const int* in_sizes, int n_in,
                              void* d_out, int out_size, void* d_ws, size_t ws_size,
                              hipStream_t stream) {
    const float* x   = (const float*)d_in[0];
    const float* W0  = (const float*)d_in[1];
    const float* U0  = (const float*)d_in[2];
    const float* b0  = (const float*)d_in[3];
    const float* W1  = (const float*)d_in[4];
    const float* U1  = (const float*)d_in[5];
    const float* b1  = (const float*)d_in[6];
    const float* Wf  = (const float*)d_in[7];
    const float* bfv = (const float*)d_in[8];
    const float* Wo  = (const float*)d_in[9];
    const float* bov = (const float*)d_in[10];
    float* out = (float*)d_out;

    lstm3_ksplit<<<BATCHN, 512, 0, stream>>>(x, W0, U0, b0, W1, U1, b1,
                                             Wf, bfv, Wo, bov, out);
}

// Round 3
// 2787.460 us; speedup vs baseline: 1.6171x; 1.0968x over previous
//
#include <hip/hip_runtime.h>

#define BATCHN 128
#define SEQT   2048
#define FEAT   64
#define UNITS  64
#define NCOL   256   // 4*UNITS gate columns
#define OUTD   6

typedef float v2f __attribute__((ext_vector_type(2)));

__device__ __forceinline__ float fast_exp2(float x) {
#if __has_builtin(__builtin_amdgcn_exp2f)
    return __builtin_amdgcn_exp2f(x);
#else
    return exp2f(x);
#endif
}
__device__ __forceinline__ float fast_rcp(float x) {
#if __has_builtin(__builtin_amdgcn_rcpf)
    return __builtin_amdgcn_rcpf(x);
#else
    return 1.0f / x;
#endif
}
__device__ __forceinline__ float sig_(float x) {
    return fast_rcp(1.0f + fast_exp2(-1.4426950408889634f * x));
}
__device__ __forceinline__ float tanh_(float x) {
    float xc = fminf(fmaxf(x, -15.0f), 15.0f);
    float e  = fast_exp2(2.8853900817779268f * xc);  // e^(2x)
    return (e - 1.0f) * fast_rcp(e + 1.0f);
}

// packed fp32 FMA: d = a*b + c on both halves (one VOP3P instr)
__device__ __forceinline__ v2f pk_fma(v2f a, v2f b, v2f c) {
    v2f d;
    asm("v_pk_fma_f32 %0, %1, %2, %3" : "=v"(d) : "v"(a), "v"(b), "v"(c));
    return d;
}

// DPP cross-lane move (VALU pipe, no LDS traffic)
template<int CTRL>
__device__ __forceinline__ float dppf(float v) {
    return __builtin_bit_cast(float, __builtin_amdgcn_update_dpp(
        0, __builtin_bit_cast(int, v), CTRL, 0xF, 0xF, true));
}
// full reduce across 8-lane k-split group (lanes differ in bits [2:0])
__device__ __forceinline__ float red8(float v) {
    v += dppf<0xB1>(v);    // quad_perm [1,0,3,2]  : xor 1
    v += dppf<0x4E>(v);    // quad_perm [2,3,0,1]  : xor 2
    v += dppf<0x141>(v);   // row_half_mirror (l^7): xor 4 after the above
    return v;
}

// load 8 contiguous floats as 4 packed pairs (2x ds/global_read_b128)
__device__ __forceinline__ void ld8(const float* __restrict__ p, v2f (&d)[4]) {
    float4 a = *(const float4*)p;
    float4 b = *(const float4*)(p + 4);
    d[0] = (v2f){a.x, a.y}; d[1] = (v2f){a.z, a.w};
    d[2] = (v2f){b.x, b.y}; d[3] = (v2f){b.z, b.w};
}

// one LSTM cell update for this thread's unit (k-chunk of 8, packed pairs)
__device__ __forceinline__ float cell_(const v2f (&WA)[4][4], const v2f (&WB)[4][4],
                                       const float (&bias)[4],
                                       const v2f (&in)[4], const v2f (&rec)[4],
                                       float& c)
{
    float z[4];
#pragma unroll
    for (int g = 0; g < 4; ++g) {
        v2f acc = (v2f){0.f, 0.f};
#pragma unroll
        for (int k = 0; k < 4; ++k) acc = pk_fma(in[k],  WA[g][k], acc);
#pragma unroll
        for (int k = 0; k < 4; ++k) acc = pk_fma(rec[k], WB[g][k], acc);
        z[g] = red8(acc.x + acc.y) + bias[g];
    }
    float ig = sig_(z[0]), fg = sig_(z[1]), gg = tanh_(z[2]), og = sig_(z[3]);
    c = fg * c + ig * gg;
    return og * tanh_(c);
}

__global__ __launch_bounds__(512, 2)
void lstm3_pk(const float* __restrict__ x,
              const float* __restrict__ W0, const float* __restrict__ U0,
              const float* __restrict__ b0,
              const float* __restrict__ W1, const float* __restrict__ U1,
              const float* __restrict__ b1,
              const float* __restrict__ Wf, const float* __restrict__ bfv,
              const float* __restrict__ Wo, const float* __restrict__ bov,
              float* __restrict__ out)
{
    const int b   = blockIdx.x;
    const int tid = threadIdx.x;   // 0..511
    const int u   = tid >> 3;      // unit 0..63 (8 consecutive lanes per unit)
    const int q   = tid & 7;       // k-split 0..7

    __shared__ __align__(16) float lh0[2][UNITS];
    __shared__ __align__(16) float lh1[2][UNITS];
    __shared__ __align__(16) float lh2[2][UNITS];
    __shared__ float lact[UNITS];

    // per-thread weights: 4 gate cols of unit u, k-chunk [8q,8q+8) as packed pairs
    v2f w0r[4][4], u0r[4][4], w1r[4][4], u1r[4][4];
    float bias0[4], bias1[4];
#pragma unroll
    for (int g = 0; g < 4; ++g) {
        const int col = (g << 6) + u;
#pragma unroll
        for (int k = 0; k < 4; ++k) {
            const int row = q * 8 + 2 * k;
            w0r[g][k] = (v2f){W0[row * NCOL + col], W0[(row + 1) * NCOL + col]};
            u0r[g][k] = (v2f){U0[row * NCOL + col], U0[(row + 1) * NCOL + col]};
            w1r[g][k] = (v2f){W1[row * NCOL + col], W1[(row + 1) * NCOL + col]};
            u1r[g][k] = (v2f){U1[row * NCOL + col], U1[(row + 1) * NCOL + col]};
        }
        bias0[g] = b0[col];
        bias1[g] = b1[col];
    }

    if (tid < UNITS) {
        lh0[0][tid] = 0.f; lh0[1][tid] = 0.f;
        lh1[0][tid] = 0.f; lh1[1][tid] = 0.f;
        lh2[0][tid] = 0.f; lh2[1][tid] = 0.f;
    }
    __syncthreads();

    const float* xrow = x + (size_t)b * SEQT * FEAT + q * 8;
    v2f xi[4];
    ld8(xrow, xi);                  // x(0)

    float c0 = 0.f, c1 = 0.f, c2 = 0.f;

    for (int t = 0; t < SEQT; ++t) {
        const int p = t & 1, pr = p ^ 1;

        // hoist all recurrent-h reads (t-1 values, stable all step) off the
        // critical path: issue 6 ds_read_b128 up front
        v2f r0[4], r1[4], r2[4];
        ld8(&lh0[pr][q * 8], r0);
        ld8(&lh1[pr][q * 8], r1);
        ld8(&lh2[pr][q * 8], r2);

        // ---- layer 0: x(t)@W0 + h0(t-1)@U0 ----
        float h0n = cell_(w0r, u0r, bias0, xi, r0, c0);
        if (q == 0) lh0[p][u] = h0n;

        // prefetch x(t+1) from global (hides under layers 1-2)
        const int tn = (t + 1 < SEQT) ? (t + 1) : (SEQT - 1);
        float4 nxa = *(const float4*)(xrow + (size_t)tn * FEAT);
        float4 nxb = *(const float4*)(xrow + (size_t)tn * FEAT + 4);
        __syncthreads();

        // ---- layer 1: h0(t)@W1 + h1(t-1)@U1 ----
        v2f f0[4];
        ld8(&lh0[p][q * 8], f0);
        float h1n = cell_(w1r, u1r, bias1, f0, r1, c1);
        if (q == 0) lh1[p][u] = h1n;
        __syncthreads();

        // ---- layer 2: h1(t)@W1 + h2(t-1)@U1 ----
        v2f f1[4];
        ld8(&lh1[p][q * 8], f1);
        float h2n = cell_(w1r, u1r, bias1, f1, r2, c2);
        if (q == 0) lh2[p][u] = h2n;
        __syncthreads();

        xi[0] = (v2f){nxa.x, nxa.y}; xi[1] = (v2f){nxa.z, nxa.w};
        xi[2] = (v2f){nxb.x, nxb.y}; xi[3] = (v2f){nxb.z, nxb.w};
    }

    // ---- dense head on final h2 (in lh2[(SEQT-1)&1]) ----
    const float* h2f = lh2[(SEQT - 1) & 1];
    if (tid < UNITS) {
        float acc = bfv[tid];
#pragma unroll
        for (int k = 0; k < UNITS; ++k) acc += h2f[k] * Wf[k * 64 + tid];
        lact[tid] = fmaxf(acc, 0.f);
    }
    __syncthreads();
    if (tid < OUTD) {
        float acc = bov[tid];
#pragma unroll
        for (int k = 0; k < UNITS; ++k) acc += lact[k] * Wo[k * OUTD + tid];
        out[b * OUTD + tid] = acc;
    }
}

extern "C" void kernel_launch(void* const* d_in, const int* in_sizes, int n_in,
                              void* d_out, int out_size, void* d_ws, size_t ws_size,
                              hipStream_t stream) {
    const float* x   = (const float*)d_in[0];
    const float* W0  = (const float*)d_in[1];
    const float* U0  = (const float*)d_in[2];
    const float* b0  = (const float*)d_in[3];
    const float* W1  = (const float*)d_in[4];
    const float* U1  = (const float*)d_in[5];
    const float* b1  = (const float*)d_in[6];
    const float* Wf  = (const float*)d_in[7];
    const float* bfv = (const float*)d_in[8];
    const float* Wo  = (const float*)d_in[9];
    const float* bov = (const float*)d_in[10];
    float* out = (float*)d_out;

    lstm3_pk<<<BATCHN, 512, 0, stream>>>(x, W0, U0, b0, W1, U1, b1,
                                         Wf, bfv, Wo, bov, out);
}

// Round 4
// 2135.991 us; speedup vs baseline: 2.1103x; 1.3050x over previous
//
#include <hip/hip_runtime.h>

#define BATCHN 128
#define SEQT   2048
#define FEAT   64
#define UNITS  64
#define NCOL   256   // 4*UNITS gate columns
#define OUTD   6

typedef float v2f __attribute__((ext_vector_type(2)));

__device__ __forceinline__ float fast_exp2(float x) {
#if __has_builtin(__builtin_amdgcn_exp2f)
    return __builtin_amdgcn_exp2f(x);
#else
    return exp2f(x);
#endif
}
__device__ __forceinline__ float fast_rcp(float x) {
#if __has_builtin(__builtin_amdgcn_rcpf)
    return __builtin_amdgcn_rcpf(x);
#else
    return 1.0f / x;
#endif
}
__device__ __forceinline__ float sig_(float x) {
    return fast_rcp(1.0f + fast_exp2(-1.4426950408889634f * x));
}
__device__ __forceinline__ float tanh_(float x) {
    float xc = fminf(fmaxf(x, -15.0f), 15.0f);
    float e  = fast_exp2(2.8853900817779268f * xc);  // e^(2x)
    return (e - 1.0f) * fast_rcp(e + 1.0f);
}

// packed fp32 FMA (one VOP3P instr, 2 MACs)
__device__ __forceinline__ v2f pk_fma(v2f a, v2f b, v2f c) {
    v2f d;
    asm("v_pk_fma_f32 %0, %1, %2, %3" : "=v"(d) : "v"(a), "v"(b), "v"(c));
    return d;
}

// DPP cross-lane (VALU pipe)
template<int CTRL>
__device__ __forceinline__ float dppf(float v) {
    return __builtin_bit_cast(float, __builtin_amdgcn_update_dpp(
        0, __builtin_bit_cast(int, v), CTRL, 0xF, 0xF, true));
}
// reduce across the 4-lane k-split quad (lanes differ in bits [1:0])
__device__ __forceinline__ float red4(float v) {
    v += dppf<0xB1>(v);    // quad_perm [1,0,3,2] : xor 1
    v += dppf<0x4E>(v);    // quad_perm [2,3,0,1] : xor 2
    return v;
}

__global__ __launch_bounds__(768, 1)
void lstm3_pipe(const float* __restrict__ x,
                const float* __restrict__ W0, const float* __restrict__ U0,
                const float* __restrict__ b0,
                const float* __restrict__ W1, const float* __restrict__ U1,
                const float* __restrict__ b1,
                const float* __restrict__ Wf, const float* __restrict__ bfv,
                const float* __restrict__ Wo, const float* __restrict__ bov,
                float* __restrict__ out)
{
    const int b   = blockIdx.x;
    const int tid = threadIdx.x;   // 0..767
    const int grp = tid >> 8;      // pipeline stage 0,1,2 (layer)
    const int lt  = tid & 255;     // 0..255 within group
    const int u   = lt >> 2;       // unit 0..63
    const int q   = lt & 3;        // k-split 0..3 (k-chunk of 16)

    __shared__ __align__(16) float lx[2][FEAT];        // x(t) staging, by parity
    __shared__ __align__(16) float lh[3][2][UNITS];    // h per layer, by parity
    __shared__ float lact[UNITS];

    // ---- weights in registers: G0 <- W0/U0 ; G1,G2 <- W1/U1  (128 VGPRs) ----
    const float* Wsel = (grp == 0) ? W0 : W1;
    const float* Usel = (grp == 0) ? U0 : U1;
    const float* bsel = (grp == 0) ? b0 : b1;

    v2f wa[4][8], wb[4][8];
    float bias[4];
#pragma unroll
    for (int g = 0; g < 4; ++g) {
        const int col = (g << 6) + u;
#pragma unroll
        for (int j = 0; j < 8; ++j) {
            const int r = q * 16 + 2 * j;
            wa[g][j] = (v2f){Wsel[r * NCOL + col], Wsel[(r + 1) * NCOL + col]};
            wb[g][j] = (v2f){Usel[r * NCOL + col], Usel[(r + 1) * NCOL + col]};
        }
        bias[g] = bsel[col];
    }

    // zero h state (both parities), preload x(0) into lx[1]
    if (tid < 3 * 2 * UNITS) ((float*)lh)[tid] = 0.f;
    const float* xbase = x + (size_t)b * SEQT * FEAT;
    if (grp == 0 && lt < 16)
        *(float4*)&lx[1][lt * 4] = *(const float4*)(xbase + lt * 4);
    __syncthreads();

    // parity-indexed LDS source/dest pointers (in: G0<-lx, G1<-h0, G2<-h1)
    const float* inP0 = (grp == 0) ? &lx[0][q * 16] : &lh[grp - 1][0][q * 16];
    const float* inP1 = (grp == 0) ? &lx[1][q * 16] : &lh[grp - 1][1][q * 16];
    const float* rcP0 = &lh[grp][0][q * 16];
    const float* rcP1 = &lh[grp][1][q * 16];

    float c = 0.f;

    for (int tk = 0; tk < SEQT + 2; ++tk) {
        const int p = tk & 1;          // write parity; reads use p^1
        const int t = tk - grp;        // this group's timestep
        const bool active = (t >= 0) && (t < SEQT);

        // loader lanes: issue global load of x(tk+1) early (lands during compute)
        float4 xg;
        const bool loading = (grp == 0) && (lt < 16) && (tk + 1 < SEQT);
        if (loading)
            xg = *(const float4*)(xbase + (size_t)(tk + 1) * FEAT + lt * 4);

        if (active) {
            const float* inP = p ? inP0 : inP1;
            const float* rcP = p ? rcP0 : rcP1;

            v2f acc[4];
#pragma unroll
            for (int g = 0; g < 4; ++g) acc[g] = (v2f){0.f, 0.f};

#pragma unroll
            for (int kc = 0; kc < 4; ++kc) {           // feed-forward input
                float4 iv = *(const float4*)(inP + kc * 4);
                v2f i0 = (v2f){iv.x, iv.y}, i1 = (v2f){iv.z, iv.w};
#pragma unroll
                for (int g = 0; g < 4; ++g) {
                    acc[g] = pk_fma(i0, wa[g][2 * kc],     acc[g]);
                    acc[g] = pk_fma(i1, wa[g][2 * kc + 1], acc[g]);
                }
            }
#pragma unroll
            for (int kc = 0; kc < 4; ++kc) {           // recurrent h
                float4 rv = *(const float4*)(rcP + kc * 4);
                v2f r0 = (v2f){rv.x, rv.y}, r1 = (v2f){rv.z, rv.w};
#pragma unroll
                for (int g = 0; g < 4; ++g) {
                    acc[g] = pk_fma(r0, wb[g][2 * kc],     acc[g]);
                    acc[g] = pk_fma(r1, wb[g][2 * kc + 1], acc[g]);
                }
            }

            float z[4];
#pragma unroll
            for (int g = 0; g < 4; ++g)
                z[g] = red4(acc[g].x + acc[g].y) + bias[g];

            float ig = sig_(z[0]), fg = sig_(z[1]);
            float gg = tanh_(z[2]), og = sig_(z[3]);
            c = fg * c + ig * gg;
            float hn = og * tanh_(c);
            if (q == 0) lh[grp][p][u] = hn;
        }

        // publish x(tk+1) for next tick's G0 read (writes parity p, reads p^1)
        if (loading)
            *(float4*)&lx[p][lt * 4] = xg;

        __syncthreads();
    }

    // ---- dense head on final h2: written at tick SEQT+1 (parity 1) ----
    const float* h2f = lh[2][(SEQT + 1) & 1];
    if (tid < UNITS) {
        float acc = bfv[tid];
#pragma unroll
        for (int k = 0; k < UNITS; ++k) acc += h2f[k] * Wf[k * 64 + tid];
        lact[tid] = fmaxf(acc, 0.f);
    }
    __syncthreads();
    if (tid < OUTD) {
        float acc = bov[tid];
#pragma unroll
        for (int k = 0; k < UNITS; ++k) acc += lact[k] * Wo[k * OUTD + tid];
        out[b * OUTD + tid] = acc;
    }
}

extern "C" void kernel_launch(void* const* d_in, const int* in_sizes, int n_in,
                              void* d_out, int out_size, void* d_ws, size_t ws_size,
                              hipStream_t stream) {
    const float* x   = (const float*)d_in[0];
    const float* W0  = (const float*)d_in[1];
    const float* U0  = (const float*)d_in[2];
    const float* b0  = (const float*)d_in[3];
    const float* W1  = (const float*)d_in[4];
    const float* U1  = (const float*)d_in[5];
    const float* b1  = (const float*)d_in[6];
    const float* Wf  = (const float*)d_in[7];
    const float* bfv = (const float*)d_in[8];
    const float* Wo  = (const float*)d_in[9];
    const float* bov = (const float*)d_in[10];
    float* out = (float*)d_out;

    lstm3_pipe<<<BATCHN, 768, 0, stream>>>(x, W0, U0, b0, W1, U1, b1,
                                           Wf, bfv, Wo, bov, out);
}